// Round 5
// baseline (232.026 us; speedup 1.0000x reference)
//
#include <hip/hip_runtime.h>

#define NGRAPHS 512
#define D 64
#define NCLS 10
#define TILE 256

// ---- indegree histogram (int atomics, L2-resident counters) ----
__global__ void k_deg(const int* __restrict__ dst, int* __restrict__ degi, int E) {
  int i = blockIdx.x * blockDim.x + threadIdx.x;
  if (i < E) atomicAdd(&degi[dst[i]], 1);
}

// ---- scan phase A: per-block (256-wide tile) sum ----
__global__ __launch_bounds__(TILE) void k_part(const int* __restrict__ degi,
                                               int* __restrict__ bsum, int n) {
  __shared__ int red[TILE];
  int t = threadIdx.x;
  int i = blockIdx.x * TILE + t;
  red[t] = (i < n) ? degi[i] : 0;
  __syncthreads();
  for (int off = TILE / 2; off > 0; off >>= 1) {
    if (t < off) red[t] += red[t + off];
    __syncthreads();
  }
  if (t == 0) bsum[blockIdx.x] = red[0];
}

// ---- scan phase B: exclusive scan of block sums (single small block) ----
__global__ __launch_bounds__(TILE) void k_scanb(const int* __restrict__ bsum,
                                                int* __restrict__ boff, int nb) {
  __shared__ int s[TILE];
  int t = threadIdx.x;
  s[t] = (t < nb) ? bsum[t] : 0;
  __syncthreads();
  for (int off = 1; off < TILE; off <<= 1) {
    int v = (t >= off) ? s[t - off] : 0;
    __syncthreads();
    s[t] += v;
    __syncthreads();
  }
  if (t < nb) boff[t] = (t > 0) ? s[t - 1] : 0;
}

// ---- scan phase C: in-block exclusive scan + offset -> rowstart; dis = rsqrt(deg+1) ----
__global__ __launch_bounds__(TILE) void k_emit(const int* __restrict__ degi,
                                               const int* __restrict__ boff,
                                               int* __restrict__ rowstart,
                                               float* __restrict__ dis, int n) {
  __shared__ int s[TILE];
  int t = threadIdx.x;
  int i = blockIdx.x * TILE + t;
  int v = (i < n) ? degi[i] : 0;
  s[t] = v;
  __syncthreads();
  for (int off = 1; off < TILE; off <<= 1) {
    int u = (t >= off) ? s[t - off] : 0;
    __syncthreads();
    s[t] += u;
    __syncthreads();
  }
  if (i < n) {
    int incl = s[t] + boff[blockIdx.x];
    rowstart[i] = incl - v;            // exclusive
    dis[i] = rsqrtf((float)v + 1.0f);
    if (i == n - 1) rowstart[n] = incl;
  }
}

// ---- fill CSR: per edge store src at rowstart[dst] + cursor (coef factored out) ----
__global__ void k_fill(const int* __restrict__ src, const int* __restrict__ dst,
                       const int* __restrict__ rowstart,
                       int* __restrict__ cursor, int* __restrict__ eci, int E) {
  int e = blockIdx.x * blockDim.x + threadIdx.x;
  if (e < E) {
    int s = src[e], d = dst[e];
    int pos = atomicAdd(&cursor[d], 1);
    eci[rowstart[d] + pos] = s;
  }
}

// ---- h' = ((optionally gathered) x @ W) * dis[node] ; W staged once per block ----
template <bool GATHER>
__global__ __launch_bounds__(256) void k_gemm(const float* __restrict__ x,
                                              const int* __restrict__ tokens,
                                              const float* __restrict__ W,
                                              const float* __restrict__ dis,
                                              float* __restrict__ h, int n) {
  __shared__ float Ws[64][64];
  __shared__ float xs[2][4][64];
  int tid = threadIdx.x;
  for (int i = tid; i < 64 * 64; i += 256) Ws[i >> 6][i & 63] = W[i];
  int nl = tid >> 6, lane = tid & 63;
  int buf = 0;
  for (int n0 = blockIdx.x * 4; n0 < n; n0 += gridDim.x * 4, buf ^= 1) {
    int node = n0 + nl;
    if (node < n) {
      size_t row = GATHER ? (size_t)tokens[node] * D : (size_t)node * D;
      xs[buf][nl][lane] = x[row + lane];
    }
    __syncthreads();
    if (node < n) {
      float acc = 0.f;
#pragma unroll
      for (int k = 0; k < 64; ++k) acc += xs[buf][nl][k] * Ws[k][lane];
      h[(size_t)node * D + lane] = acc * dis[node];
    }
  }
}

// ---- gather-aggregate: wave = node; lane = (edge-slot[2b], chan-group[4b]);
//      acc = sum of h'[src] rows; out = relu(dis[d]*(acc + h'[d]) + b) ----
__global__ __launch_bounds__(256) void k_agg(const float4* __restrict__ h4,
                                             const int* __restrict__ eci,
                                             const int* __restrict__ rowstart,
                                             const float* __restrict__ dis,
                                             const float4* __restrict__ b4,
                                             float4* __restrict__ out, int n) {
  int tid = blockIdx.x * blockDim.x + threadIdx.x;
  int node = tid >> 6;
  int lane = tid & 63;
  int slot = lane >> 4;    // 0..3: which edge of a 4-edge group
  int cg   = lane & 15;    // channel group: channels 4*cg .. 4*cg+3
  if (node >= n) return;
  int beg = rowstart[node], end = rowstart[node + 1];
  float4 acc = make_float4(0.f, 0.f, 0.f, 0.f);
  int i = beg + slot;
  for (; i + 4 < end; i += 8) {           // 2 edges per slot per trip, 8 gathers in flight
    int s0 = eci[i];
    int s1 = eci[i + 4];
    float4 v0 = h4[(size_t)s0 * 16 + cg];
    float4 v1 = h4[(size_t)s1 * 16 + cg];
    acc.x += v0.x + v1.x; acc.y += v0.y + v1.y;
    acc.z += v0.z + v1.z; acc.w += v0.w + v1.w;
  }
  if (i < end) {
    float4 v = h4[(size_t)eci[i] * 16 + cg];
    acc.x += v.x; acc.y += v.y; acc.z += v.z; acc.w += v.w;
  }
  // reduce the 4 edge slots (lane bits 4 and 5)
  acc.x += __shfl_xor(acc.x, 16, 64);
  acc.y += __shfl_xor(acc.y, 16, 64);
  acc.z += __shfl_xor(acc.z, 16, 64);
  acc.w += __shfl_xor(acc.w, 16, 64);
  acc.x += __shfl_xor(acc.x, 32, 64);
  acc.y += __shfl_xor(acc.y, 32, 64);
  acc.z += __shfl_xor(acc.z, 32, 64);
  acc.w += __shfl_xor(acc.w, 32, 64);
  if (slot == 0) {
    float dd = dis[node];
    float4 hv = h4[(size_t)node * 16 + cg];
    float4 bv = b4[cg];
    acc.x = fmaxf((acc.x + hv.x) * dd + bv.x, 0.f);
    acc.y = fmaxf((acc.y + hv.y) * dd + bv.y, 0.f);
    acc.z = fmaxf((acc.z + hv.z) * dd + bv.z, 0.f);
    acc.w = fmaxf((acc.w + hv.w) * dd + bv.w, 0.f);
    out[(size_t)node * 16 + cg] = acc;
  }
}

// ---- mean-pool per graph: one block per graph, bounds via binary search on sorted batch ----
__device__ __forceinline__ int lower_bound(const int* __restrict__ a, int n, int v) {
  int lo = 0, hi = n;
  while (lo < hi) {
    int m = (lo + hi) >> 1;
    if (a[m] < v) lo = m + 1; else hi = m;
  }
  return lo;
}

__global__ __launch_bounds__(256) void k_pool(const float* __restrict__ x,
                                              const int* __restrict__ batch,
                                              float* __restrict__ pooled, int n) {
  __shared__ float red[4][64];
  int g = blockIdx.x;
  int s = lower_bound(batch, n, g);
  int e = lower_bound(batch, n, g + 1);
  int w = threadIdx.x >> 6, lane = threadIdx.x & 63;
  float acc = 0.f;
  for (int i = s + w; i < e; i += 4) acc += x[(size_t)i * D + lane];
  red[w][lane] = acc;
  __syncthreads();
  if (w == 0) {
    float v = red[0][lane] + red[1][lane] + red[2][lane] + red[3][lane];
    float inv = 1.0f / fmaxf((float)(e - s), 1.0f);
    pooled[(size_t)g * D + lane] = v * inv;
  }
}

// ---- linear head ----
__global__ void k_final(const float* __restrict__ pooled, const float* __restrict__ lw,
                        const float* __restrict__ lb, float* __restrict__ out) {
  int i = blockIdx.x * blockDim.x + threadIdx.x;
  if (i < NGRAPHS * NCLS) {
    int g = i / NCLS, c = i % NCLS;
    float acc = lb[c];
#pragma unroll
    for (int k = 0; k < D; ++k) acc += pooled[(size_t)g * D + k] * lw[k * NCLS + c];
    out[i] = acc;
  }
}

extern "C" void kernel_launch(void* const* d_in, const int* in_sizes, int n_in,
                              void* d_out, int out_size, void* d_ws, size_t ws_size,
                              hipStream_t stream) {
  const int* tokens = (const int*)d_in[0];
  const int* edge   = (const int*)d_in[1];
  const int* batch  = (const int*)d_in[2];
  const float* emb  = (const float*)d_in[3];
  const float* W1   = (const float*)d_in[4];
  const float* b1   = (const float*)d_in[5];
  const float* W2   = (const float*)d_in[6];
  const float* b2   = (const float*)d_in[7];
  const float* lw   = (const float*)d_in[8];
  const float* lb   = (const float*)d_in[9];
  float* out = (float*)d_out;

  const int N = in_sizes[0];
  const int E = in_sizes[1] / 2;
  const int* src  = edge;
  const int* dstv = edge + E;

  const int nb = (N + TILE - 1) / TILE;   // scan blocks (196 for N=50000)

  char* ws = (char*)d_ws;
  size_t off = 0;
  auto alloc = [&](size_t bytes) {
    void* p = ws + off;
    off += (bytes + 255) & ~(size_t)255;
    return p;
  };
  float* A        = (float*)alloc((size_t)N * D * sizeof(float));   // h' buffer
  float* B        = (float*)alloc((size_t)N * D * sizeof(float));   // x buffer
  int*   eci      = (int*)alloc((size_t)E * sizeof(int));            // CSR src indices
  float* dis      = (float*)alloc((size_t)N * sizeof(float));
  int*   degi     = (int*)alloc((size_t)N * sizeof(int));
  int*   cursor   = (int*)alloc((size_t)N * sizeof(int));
  int*   rowstart = (int*)alloc(((size_t)N + 1) * sizeof(int));
  int*   bsum     = (int*)alloc((size_t)nb * sizeof(int));
  int*   boff     = (int*)alloc((size_t)nb * sizeof(int));
  float* pooled   = (float*)alloc((size_t)NGRAPHS * D * sizeof(float));

  hipMemsetAsync(degi, 0, (size_t)N * sizeof(int), stream);
  hipMemsetAsync(cursor, 0, (size_t)N * sizeof(int), stream);

  // CSR build (shared by both layers)
  k_deg<<<(E + 255) / 256, 256, 0, stream>>>(dstv, degi, E);
  k_part<<<nb, TILE, 0, stream>>>(degi, bsum, N);
  k_scanb<<<1, TILE, 0, stream>>>(bsum, boff, nb);
  k_emit<<<nb, TILE, 0, stream>>>(degi, boff, rowstart, dis, N);
  k_fill<<<(E + 255) / 256, 256, 0, stream>>>(src, dstv, rowstart, cursor, eci, E);

  const int gemmGrid = 2048;

  // layer 1
  k_gemm<true><<<gemmGrid, 256, 0, stream>>>(emb, tokens, W1, dis, A, N);
  k_agg<<<(N + 3) / 4, 256, 0, stream>>>((const float4*)A, eci, rowstart, dis,
                                         (const float4*)b1, (float4*)B, N);

  // layer 2
  k_gemm<false><<<gemmGrid, 256, 0, stream>>>(B, nullptr, W2, dis, A, N);
  k_agg<<<(N + 3) / 4, 256, 0, stream>>>((const float4*)A, eci, rowstart, dis,
                                         (const float4*)b2, (float4*)B, N);

  // pooling + head
  k_pool<<<NGRAPHS, 256, 0, stream>>>(B, batch, pooled, N);
  k_final<<<(NGRAPHS * NCLS + 255) / 256, 256, 0, stream>>>(pooled, lw, lb, out);
}

// Round 6
// 196.627 us; speedup vs baseline: 1.1800x; 1.1800x over previous
//
#include <hip/hip_runtime.h>

#define NGRAPHS 512
#define D 64
#define NCLS 10
#define TILE 256

// ---- indegree histogram; atomic return value IS the edge's within-node rank ----
__global__ void k_deg(const int* __restrict__ dst, int* __restrict__ degi,
                      int* __restrict__ rank, int E) {
  int i = blockIdx.x * blockDim.x + threadIdx.x;
  if (i < E) rank[i] = atomicAdd(&degi[dst[i]], 1);
}

// ---- scan phase A: per-block (256-wide tile) sum ----
__global__ __launch_bounds__(TILE) void k_part(const int* __restrict__ degi,
                                               int* __restrict__ bsum, int n) {
  __shared__ int red[TILE];
  int t = threadIdx.x;
  int i = blockIdx.x * TILE + t;
  red[t] = (i < n) ? degi[i] : 0;
  __syncthreads();
  for (int off = TILE / 2; off > 0; off >>= 1) {
    if (t < off) red[t] += red[t + off];
    __syncthreads();
  }
  if (t == 0) bsum[blockIdx.x] = red[0];
}

// ---- scan phase B: exclusive scan of block sums (single small block) ----
__global__ __launch_bounds__(TILE) void k_scanb(const int* __restrict__ bsum,
                                                int* __restrict__ boff, int nb) {
  __shared__ int s[TILE];
  int t = threadIdx.x;
  s[t] = (t < nb) ? bsum[t] : 0;
  __syncthreads();
  for (int off = 1; off < TILE; off <<= 1) {
    int v = (t >= off) ? s[t - off] : 0;
    __syncthreads();
    s[t] += v;
    __syncthreads();
  }
  if (t < nb) boff[t] = (t > 0) ? s[t - 1] : 0;
}

// ---- scan phase C: in-block exclusive scan + offset -> rowstart; dis = rsqrt(deg+1) ----
__global__ __launch_bounds__(TILE) void k_emit(const int* __restrict__ degi,
                                               const int* __restrict__ boff,
                                               int* __restrict__ rowstart,
                                               float* __restrict__ dis, int n) {
  __shared__ int s[TILE];
  int t = threadIdx.x;
  int i = blockIdx.x * TILE + t;
  int v = (i < n) ? degi[i] : 0;
  s[t] = v;
  __syncthreads();
  for (int off = 1; off < TILE; off <<= 1) {
    int u = (t >= off) ? s[t - off] : 0;
    __syncthreads();
    s[t] += u;
    __syncthreads();
  }
  if (i < n) {
    int incl = s[t] + boff[blockIdx.x];
    rowstart[i] = incl - v;            // exclusive
    dis[i] = rsqrtf((float)v + 1.0f);
    if (i == n - 1) rowstart[n] = incl;
  }
}

// ---- fill CSR: atomic-free — slot precomputed as rank[e] ----
__global__ void k_fill(const int* __restrict__ src, const int* __restrict__ dst,
                       const int* __restrict__ rank, const int* __restrict__ rowstart,
                       int* __restrict__ eci, int E) {
  int e = blockIdx.x * blockDim.x + threadIdx.x;
  if (e < E) {
    eci[rowstart[dst[e]] + rank[e]] = src[e];
  }
}

// ---- h' = ((optionally gathered) x @ W) * dis[node] ; W staged once per block ----
template <bool GATHER>
__global__ __launch_bounds__(256) void k_gemm(const float* __restrict__ x,
                                              const int* __restrict__ tokens,
                                              const float* __restrict__ W,
                                              const float* __restrict__ dis,
                                              float* __restrict__ h, int n) {
  __shared__ float Ws[64][64];
  __shared__ float xs[2][4][64];
  int tid = threadIdx.x;
  for (int i = tid; i < 64 * 64; i += 256) Ws[i >> 6][i & 63] = W[i];
  int nl = tid >> 6, lane = tid & 63;
  int buf = 0;
  for (int n0 = blockIdx.x * 4; n0 < n; n0 += gridDim.x * 4, buf ^= 1) {
    int node = n0 + nl;
    if (node < n) {
      size_t row = GATHER ? (size_t)tokens[node] * D : (size_t)node * D;
      xs[buf][nl][lane] = x[row + lane];
    }
    __syncthreads();
    if (node < n) {
      float acc = 0.f;
#pragma unroll
      for (int k = 0; k < 64; ++k) acc += xs[buf][nl][k] * Ws[k][lane];
      h[(size_t)node * D + lane] = acc * dis[node];
    }
  }
}

// ---- gather-aggregate: wave = node; lane = (edge-slot[2b], chan-group[4b]);
//      acc = sum of h'[src] rows; out = relu(dis[d]*(acc + h'[d]) + b) ----
__global__ __launch_bounds__(256) void k_agg(const float4* __restrict__ h4,
                                             const int* __restrict__ eci,
                                             const int* __restrict__ rowstart,
                                             const float* __restrict__ dis,
                                             const float4* __restrict__ b4,
                                             float4* __restrict__ out, int n) {
  int tid = blockIdx.x * blockDim.x + threadIdx.x;
  int node = tid >> 6;
  int lane = tid & 63;
  int slot = lane >> 4;    // 0..3: which edge of a 4-edge group
  int cg   = lane & 15;    // channel group: channels 4*cg .. 4*cg+3
  if (node >= n) return;
  int beg = rowstart[node], end = rowstart[node + 1];
  float4 acc = make_float4(0.f, 0.f, 0.f, 0.f);
  int i = beg + slot;
  for (; i + 4 < end; i += 8) {           // 2 edges per slot per trip, 8 gathers in flight
    int s0 = eci[i];
    int s1 = eci[i + 4];
    float4 v0 = h4[(size_t)s0 * 16 + cg];
    float4 v1 = h4[(size_t)s1 * 16 + cg];
    acc.x += v0.x + v1.x; acc.y += v0.y + v1.y;
    acc.z += v0.z + v1.z; acc.w += v0.w + v1.w;
  }
  if (i < end) {
    float4 v = h4[(size_t)eci[i] * 16 + cg];
    acc.x += v.x; acc.y += v.y; acc.z += v.z; acc.w += v.w;
  }
  // reduce the 4 edge slots (lane bits 4 and 5)
  acc.x += __shfl_xor(acc.x, 16, 64);
  acc.y += __shfl_xor(acc.y, 16, 64);
  acc.z += __shfl_xor(acc.z, 16, 64);
  acc.w += __shfl_xor(acc.w, 16, 64);
  acc.x += __shfl_xor(acc.x, 32, 64);
  acc.y += __shfl_xor(acc.y, 32, 64);
  acc.z += __shfl_xor(acc.z, 32, 64);
  acc.w += __shfl_xor(acc.w, 32, 64);
  if (slot == 0) {
    float dd = dis[node];
    float4 hv = h4[(size_t)node * 16 + cg];
    float4 bv = b4[cg];
    acc.x = fmaxf((acc.x + hv.x) * dd + bv.x, 0.f);
    acc.y = fmaxf((acc.y + hv.y) * dd + bv.y, 0.f);
    acc.z = fmaxf((acc.z + hv.z) * dd + bv.z, 0.f);
    acc.w = fmaxf((acc.w + hv.w) * dd + bv.w, 0.f);
    out[(size_t)node * 16 + cg] = acc;
  }
}

// ---- mean-pool per graph: one block per graph, bounds via binary search on sorted batch ----
__device__ __forceinline__ int lower_bound(const int* __restrict__ a, int n, int v) {
  int lo = 0, hi = n;
  while (lo < hi) {
    int m = (lo + hi) >> 1;
    if (a[m] < v) lo = m + 1; else hi = m;
  }
  return lo;
}

__global__ __launch_bounds__(256) void k_pool(const float* __restrict__ x,
                                              const int* __restrict__ batch,
                                              float* __restrict__ pooled, int n) {
  __shared__ float red[4][64];
  int g = blockIdx.x;
  int s = lower_bound(batch, n, g);
  int e = lower_bound(batch, n, g + 1);
  int w = threadIdx.x >> 6, lane = threadIdx.x & 63;
  float acc = 0.f;
  for (int i = s + w; i < e; i += 4) acc += x[(size_t)i * D + lane];
  red[w][lane] = acc;
  __syncthreads();
  if (w == 0) {
    float v = red[0][lane] + red[1][lane] + red[2][lane] + red[3][lane];
    float inv = 1.0f / fmaxf((float)(e - s), 1.0f);
    pooled[(size_t)g * D + lane] = v * inv;
  }
}

// ---- linear head ----
__global__ void k_final(const float* __restrict__ pooled, const float* __restrict__ lw,
                        const float* __restrict__ lb, float* __restrict__ out) {
  int i = blockIdx.x * blockDim.x + threadIdx.x;
  if (i < NGRAPHS * NCLS) {
    int g = i / NCLS, c = i % NCLS;
    float acc = lb[c];
#pragma unroll
    for (int k = 0; k < D; ++k) acc += pooled[(size_t)g * D + k] * lw[k * NCLS + c];
    out[i] = acc;
  }
}

extern "C" void kernel_launch(void* const* d_in, const int* in_sizes, int n_in,
                              void* d_out, int out_size, void* d_ws, size_t ws_size,
                              hipStream_t stream) {
  const int* tokens = (const int*)d_in[0];
  const int* edge   = (const int*)d_in[1];
  const int* batch  = (const int*)d_in[2];
  const float* emb  = (const float*)d_in[3];
  const float* W1   = (const float*)d_in[4];
  const float* b1   = (const float*)d_in[5];
  const float* W2   = (const float*)d_in[6];
  const float* b2   = (const float*)d_in[7];
  const float* lw   = (const float*)d_in[8];
  const float* lb   = (const float*)d_in[9];
  float* out = (float*)d_out;

  const int N = in_sizes[0];
  const int E = in_sizes[1] / 2;
  const int* src  = edge;
  const int* dstv = edge + E;

  const int nb = (N + TILE - 1) / TILE;   // scan blocks (196 for N=50000)

  char* ws = (char*)d_ws;
  size_t off = 0;
  auto alloc = [&](size_t bytes) {
    void* p = ws + off;
    off += (bytes + 255) & ~(size_t)255;
    return p;
  };
  float* A        = (float*)alloc((size_t)N * D * sizeof(float));   // h' buffer
  float* B        = (float*)alloc((size_t)N * D * sizeof(float));   // x buffer
  int*   eci      = (int*)alloc((size_t)E * sizeof(int));            // CSR src indices
  int*   rank     = (int*)alloc((size_t)E * sizeof(int));            // within-node slot
  float* dis      = (float*)alloc((size_t)N * sizeof(float));
  int*   degi     = (int*)alloc((size_t)N * sizeof(int));
  int*   rowstart = (int*)alloc(((size_t)N + 1) * sizeof(int));
  int*   bsum     = (int*)alloc((size_t)nb * sizeof(int));
  int*   boff     = (int*)alloc((size_t)nb * sizeof(int));
  float* pooled   = (float*)alloc((size_t)NGRAPHS * D * sizeof(float));

  hipMemsetAsync(degi, 0, (size_t)N * sizeof(int), stream);

  // CSR build (shared by both layers)
  k_deg<<<(E + 255) / 256, 256, 0, stream>>>(dstv, degi, rank, E);
  k_part<<<nb, TILE, 0, stream>>>(degi, bsum, N);
  k_scanb<<<1, TILE, 0, stream>>>(bsum, boff, nb);
  k_emit<<<nb, TILE, 0, stream>>>(degi, boff, rowstart, dis, N);
  k_fill<<<(E + 255) / 256, 256, 0, stream>>>(src, dstv, rank, rowstart, eci, E);

  const int gemmGrid = 2048;

  // layer 1
  k_gemm<true><<<gemmGrid, 256, 0, stream>>>(emb, tokens, W1, dis, A, N);
  k_agg<<<(N + 3) / 4, 256, 0, stream>>>((const float4*)A, eci, rowstart, dis,
                                         (const float4*)b1, (float4*)B, N);

  // layer 2
  k_gemm<false><<<gemmGrid, 256, 0, stream>>>(B, nullptr, W2, dis, A, N);
  k_agg<<<(N + 3) / 4, 256, 0, stream>>>((const float4*)A, eci, rowstart, dis,
                                         (const float4*)b2, (float4*)B, N);

  // pooling + head
  k_pool<<<NGRAPHS, 256, 0, stream>>>(B, batch, pooled, N);
  k_final<<<(NGRAPHS * NCLS + 255) / 256, 256, 0, stream>>>(pooled, lw, lb, out);
}

// Round 7
// 189.715 us; speedup vs baseline: 1.2230x; 1.0364x over previous
//
#include <hip/hip_runtime.h>

#define NGRAPHS 512
#define D 64
#define NCLS 10
#define TILE 256

// ---- indegree histogram; atomic return value IS the edge's within-node rank ----
__global__ void k_deg(const int* __restrict__ dst, int* __restrict__ degi,
                      int* __restrict__ rank, int E) {
  int i = blockIdx.x * blockDim.x + threadIdx.x;
  if (i < E) rank[i] = atomicAdd(&degi[dst[i]], 1);
}

// ---- scan phase A: per-block (256-wide tile) sum ----
__global__ __launch_bounds__(TILE) void k_part(const int* __restrict__ degi,
                                               int* __restrict__ bsum, int n) {
  __shared__ int red[TILE];
  int t = threadIdx.x;
  int i = blockIdx.x * TILE + t;
  red[t] = (i < n) ? degi[i] : 0;
  __syncthreads();
  for (int off = TILE / 2; off > 0; off >>= 1) {
    if (t < off) red[t] += red[t + off];
    __syncthreads();
  }
  if (t == 0) bsum[blockIdx.x] = red[0];
}

// ---- scan phase B: exclusive scan of block sums (single small block) ----
__global__ __launch_bounds__(TILE) void k_scanb(const int* __restrict__ bsum,
                                                int* __restrict__ boff, int nb) {
  __shared__ int s[TILE];
  int t = threadIdx.x;
  s[t] = (t < nb) ? bsum[t] : 0;
  __syncthreads();
  for (int off = 1; off < TILE; off <<= 1) {
    int v = (t >= off) ? s[t - off] : 0;
    __syncthreads();
    s[t] += v;
    __syncthreads();
  }
  if (t < nb) boff[t] = (t > 0) ? s[t - 1] : 0;
}

// ---- scan phase C: in-block exclusive scan + offset -> rowstart; dis = rsqrt(deg+1) ----
__global__ __launch_bounds__(TILE) void k_emit(const int* __restrict__ degi,
                                               const int* __restrict__ boff,
                                               int* __restrict__ rowstart,
                                               float* __restrict__ dis, int n) {
  __shared__ int s[TILE];
  int t = threadIdx.x;
  int i = blockIdx.x * TILE + t;
  int v = (i < n) ? degi[i] : 0;
  s[t] = v;
  __syncthreads();
  for (int off = 1; off < TILE; off <<= 1) {
    int u = (t >= off) ? s[t - off] : 0;
    __syncthreads();
    s[t] += u;
    __syncthreads();
  }
  if (i < n) {
    int incl = s[t] + boff[blockIdx.x];
    rowstart[i] = incl - v;            // exclusive
    dis[i] = rsqrtf((float)v + 1.0f);
    if (i == n - 1) rowstart[n] = incl;
  }
}

// ---- fill CSR: atomic-free — slot precomputed as rank[e] ----
__global__ void k_fill(const int* __restrict__ src, const int* __restrict__ dst,
                       const int* __restrict__ rank, const int* __restrict__ rowstart,
                       int* __restrict__ eci, int E) {
  int e = blockIdx.x * blockDim.x + threadIdx.x;
  if (e < E) {
    eci[rowstart[dst[e]] + rank[e]] = src[e];
  }
}

// ---- layer-1 GEMM: wave per node; lane=(slot[2b],cg[4b]); slot partitions K.
//      h' = (emb[token] @ W1) * dis[node] ----
template <bool GATHER>
__global__ __launch_bounds__(256) void k_gemm1(const float* __restrict__ x,
                                               const int* __restrict__ tokens,
                                               const float* __restrict__ W,
                                               const float* __restrict__ dis,
                                               float4* __restrict__ h4, int n) {
  __shared__ float Ws[64 * 64];
  int tid = threadIdx.x;
  for (int i = tid; i < 64 * 64; i += 256) Ws[i] = W[i];
  __syncthreads();
  const float4* Ws4 = (const float4*)Ws;
  int w = tid >> 6, lane = tid & 63;
  int cg = lane & 15;
  int kb = lane & 48;                 // 16 * slot
  for (int node = blockIdx.x * 4 + w; node < n; node += gridDim.x * 4) {
    size_t row = GATHER ? (size_t)tokens[node] * D : (size_t)node * D;
    float xval = x[row + lane];       // lane = input channel
    float4 acc = make_float4(0.f, 0.f, 0.f, 0.f);
#pragma unroll
    for (int p = 0; p < 16; ++p) {
      float xv = __shfl(xval, kb + p, 64);        // x[k], k = kb+p
      float4 wv = Ws4[(kb + p) * 16 + cg];        // W[k][4cg..4cg+3]
      acc.x += xv * wv.x; acc.y += xv * wv.y;
      acc.z += xv * wv.z; acc.w += xv * wv.w;
    }
    // butterfly over slot bits -> all lanes hold full sum
    acc.x += __shfl_xor(acc.x, 16, 64); acc.y += __shfl_xor(acc.y, 16, 64);
    acc.z += __shfl_xor(acc.z, 16, 64); acc.w += __shfl_xor(acc.w, 16, 64);
    acc.x += __shfl_xor(acc.x, 32, 64); acc.y += __shfl_xor(acc.y, 32, 64);
    acc.z += __shfl_xor(acc.z, 32, 64); acc.w += __shfl_xor(acc.w, 32, 64);
    float dd = dis[node];
    if (lane < 16) {
      h4[(size_t)node * 16 + cg] =
          make_float4(acc.x * dd, acc.y * dd, acc.z * dd, acc.w * dd);
    }
  }
}

// ---- fused: agg(layer1) + relu + GEMM(W2) + *dis -> h2'.
//      wave per node; agg: slot=edge-group, cg=channels; gemm: slot partitions K ----
__global__ __launch_bounds__(256) void k_aggemm(const float4* __restrict__ h4,
                                                const int* __restrict__ eci,
                                                const int* __restrict__ rowstart,
                                                const float* __restrict__ dis,
                                                const float4* __restrict__ b4,
                                                const float* __restrict__ W2,
                                                float4* __restrict__ h2, int n) {
  __shared__ float Ws[64 * 64];
  int tid = threadIdx.x;
  for (int i = tid; i < 64 * 64; i += 256) Ws[i] = W2[i];
  __syncthreads();
  const float4* Ws4 = (const float4*)Ws;
  int w = tid >> 6, lane = tid & 63;
  int slot = lane >> 4, cg = lane & 15;
  int kb = lane & 48;
  for (int node = blockIdx.x * 4 + w; node < n; node += gridDim.x * 4) {
    int beg = rowstart[node], end = rowstart[node + 1];
    float4 acc = make_float4(0.f, 0.f, 0.f, 0.f);
    int i = beg + slot;
    for (; i + 12 < end; i += 16) {   // 4 edges per slot per trip, 16 gathers in flight
      int s0 = eci[i], s1 = eci[i + 4], s2 = eci[i + 8], s3 = eci[i + 12];
      float4 v0 = h4[(size_t)s0 * 16 + cg];
      float4 v1 = h4[(size_t)s1 * 16 + cg];
      float4 v2 = h4[(size_t)s2 * 16 + cg];
      float4 v3 = h4[(size_t)s3 * 16 + cg];
      acc.x += (v0.x + v1.x) + (v2.x + v3.x);
      acc.y += (v0.y + v1.y) + (v2.y + v3.y);
      acc.z += (v0.z + v1.z) + (v2.z + v3.z);
      acc.w += (v0.w + v1.w) + (v2.w + v3.w);
    }
    for (; i < end; i += 4) {
      float4 v = h4[(size_t)eci[i] * 16 + cg];
      acc.x += v.x; acc.y += v.y; acc.z += v.z; acc.w += v.w;
    }
    acc.x += __shfl_xor(acc.x, 16, 64); acc.y += __shfl_xor(acc.y, 16, 64);
    acc.z += __shfl_xor(acc.z, 16, 64); acc.w += __shfl_xor(acc.w, 16, 64);
    acc.x += __shfl_xor(acc.x, 32, 64); acc.y += __shfl_xor(acc.y, 32, 64);
    acc.z += __shfl_xor(acc.z, 32, 64); acc.w += __shfl_xor(acc.w, 32, 64);
    float dd = dis[node];
    float4 hv = h4[(size_t)node * 16 + cg];
    float4 bv = b4[cg];
    float4 x2;                         // valid (identical) on all lanes
    x2.x = fmaxf((acc.x + hv.x) * dd + bv.x, 0.f);
    x2.y = fmaxf((acc.y + hv.y) * dd + bv.y, 0.f);
    x2.z = fmaxf((acc.z + hv.z) * dd + bv.z, 0.f);
    x2.w = fmaxf((acc.w + hv.w) * dd + bv.w, 0.f);
    // GEMM: h2[out] = sum_k x2[k] * W2[k][out]; lane covers k in [kb, kb+16)
    float4 g = make_float4(0.f, 0.f, 0.f, 0.f);
#pragma unroll
    for (int p = 0; p < 4; ++p) {
      int sl = (kb >> 2) + p;          // lane holding x2[kb+4p .. kb+4p+3]
      float xv0 = __shfl(x2.x, sl, 64);
      float xv1 = __shfl(x2.y, sl, 64);
      float xv2 = __shfl(x2.z, sl, 64);
      float xv3 = __shfl(x2.w, sl, 64);
      float4 w0 = Ws4[(kb + 4 * p + 0) * 16 + cg];
      float4 w1 = Ws4[(kb + 4 * p + 1) * 16 + cg];
      float4 w2 = Ws4[(kb + 4 * p + 2) * 16 + cg];
      float4 w3 = Ws4[(kb + 4 * p + 3) * 16 + cg];
      g.x += xv0 * w0.x + xv1 * w1.x + xv2 * w2.x + xv3 * w3.x;
      g.y += xv0 * w0.y + xv1 * w1.y + xv2 * w2.y + xv3 * w3.y;
      g.z += xv0 * w0.z + xv1 * w1.z + xv2 * w2.z + xv3 * w3.z;
      g.w += xv0 * w0.w + xv1 * w1.w + xv2 * w2.w + xv3 * w3.w;
    }
    g.x += __shfl_xor(g.x, 16, 64); g.y += __shfl_xor(g.y, 16, 64);
    g.z += __shfl_xor(g.z, 16, 64); g.w += __shfl_xor(g.w, 16, 64);
    g.x += __shfl_xor(g.x, 32, 64); g.y += __shfl_xor(g.y, 32, 64);
    g.z += __shfl_xor(g.z, 32, 64); g.w += __shfl_xor(g.w, 32, 64);
    if (lane < 16) {
      h2[(size_t)node * 16 + cg] =
          make_float4(g.x * dd, g.y * dd, g.z * dd, g.w * dd);
    }
  }
}

// ---- layer-2 aggregate: gather + relu, write x3 ----
__global__ __launch_bounds__(256) void k_agg2(const float4* __restrict__ h4,
                                              const int* __restrict__ eci,
                                              const int* __restrict__ rowstart,
                                              const float* __restrict__ dis,
                                              const float4* __restrict__ b4,
                                              float4* __restrict__ out, int n) {
  int tid = blockIdx.x * blockDim.x + threadIdx.x;
  int node = tid >> 6;
  int lane = tid & 63;
  int slot = lane >> 4;
  int cg = lane & 15;
  if (node >= n) return;
  int beg = rowstart[node], end = rowstart[node + 1];
  float4 acc = make_float4(0.f, 0.f, 0.f, 0.f);
  int i = beg + slot;
  for (; i + 12 < end; i += 16) {
    int s0 = eci[i], s1 = eci[i + 4], s2 = eci[i + 8], s3 = eci[i + 12];
    float4 v0 = h4[(size_t)s0 * 16 + cg];
    float4 v1 = h4[(size_t)s1 * 16 + cg];
    float4 v2 = h4[(size_t)s2 * 16 + cg];
    float4 v3 = h4[(size_t)s3 * 16 + cg];
    acc.x += (v0.x + v1.x) + (v2.x + v3.x);
    acc.y += (v0.y + v1.y) + (v2.y + v3.y);
    acc.z += (v0.z + v1.z) + (v2.z + v3.z);
    acc.w += (v0.w + v1.w) + (v2.w + v3.w);
  }
  for (; i < end; i += 4) {
    float4 v = h4[(size_t)eci[i] * 16 + cg];
    acc.x += v.x; acc.y += v.y; acc.z += v.z; acc.w += v.w;
  }
  acc.x += __shfl_xor(acc.x, 16, 64); acc.y += __shfl_xor(acc.y, 16, 64);
  acc.z += __shfl_xor(acc.z, 16, 64); acc.w += __shfl_xor(acc.w, 16, 64);
  acc.x += __shfl_xor(acc.x, 32, 64); acc.y += __shfl_xor(acc.y, 32, 64);
  acc.z += __shfl_xor(acc.z, 32, 64); acc.w += __shfl_xor(acc.w, 32, 64);
  if (slot == 0) {
    float dd = dis[node];
    float4 hv = h4[(size_t)node * 16 + cg];
    float4 bv = b4[cg];
    acc.x = fmaxf((acc.x + hv.x) * dd + bv.x, 0.f);
    acc.y = fmaxf((acc.y + hv.y) * dd + bv.y, 0.f);
    acc.z = fmaxf((acc.z + hv.z) * dd + bv.z, 0.f);
    acc.w = fmaxf((acc.w + hv.w) * dd + bv.w, 0.f);
    out[(size_t)node * 16 + cg] = acc;
  }
}

// ---- fused mean-pool + linear head: one block per graph ----
__device__ __forceinline__ int lower_bound(const int* __restrict__ a, int n, int v) {
  int lo = 0, hi = n;
  while (lo < hi) {
    int m = (lo + hi) >> 1;
    if (a[m] < v) lo = m + 1; else hi = m;
  }
  return lo;
}

__global__ __launch_bounds__(256) void k_poolfinal(const float* __restrict__ x,
                                                   const int* __restrict__ batch,
                                                   const float* __restrict__ lw,
                                                   const float* __restrict__ lb,
                                                   float* __restrict__ out, int n) {
  __shared__ float red[4][64];
  __shared__ float pooled[64];
  int g = blockIdx.x;
  int s = lower_bound(batch, n, g);
  int e = lower_bound(batch, n, g + 1);
  int w = threadIdx.x >> 6, lane = threadIdx.x & 63;
  float acc = 0.f;
  for (int i = s + w; i < e; i += 4) acc += x[(size_t)i * D + lane];
  red[w][lane] = acc;
  __syncthreads();
  if (w == 0) {
    float v = red[0][lane] + red[1][lane] + red[2][lane] + red[3][lane];
    pooled[lane] = v / fmaxf((float)(e - s), 1.0f);
  }
  __syncthreads();
  if (threadIdx.x < NCLS) {
    int c = threadIdx.x;
    float a = lb[c];
#pragma unroll
    for (int k = 0; k < D; ++k) a += pooled[k] * lw[k * NCLS + c];
    out[g * NCLS + c] = a;
  }
}

extern "C" void kernel_launch(void* const* d_in, const int* in_sizes, int n_in,
                              void* d_out, int out_size, void* d_ws, size_t ws_size,
                              hipStream_t stream) {
  const int* tokens = (const int*)d_in[0];
  const int* edge   = (const int*)d_in[1];
  const int* batch  = (const int*)d_in[2];
  const float* emb  = (const float*)d_in[3];
  const float* W1   = (const float*)d_in[4];
  const float* b1   = (const float*)d_in[5];
  const float* W2   = (const float*)d_in[6];
  const float* b2   = (const float*)d_in[7];
  const float* lw   = (const float*)d_in[8];
  const float* lb   = (const float*)d_in[9];
  float* out = (float*)d_out;

  const int N = in_sizes[0];
  const int E = in_sizes[1] / 2;
  const int* src  = edge;
  const int* dstv = edge + E;

  const int nb = (N + TILE - 1) / TILE;   // scan blocks (196 for N=50000)

  char* ws = (char*)d_ws;
  size_t off = 0;
  auto alloc = [&](size_t bytes) {
    void* p = ws + off;
    off += (bytes + 255) & ~(size_t)255;
    return p;
  };
  float* A        = (float*)alloc((size_t)N * D * sizeof(float));   // h1' / x3 buffer
  float* B        = (float*)alloc((size_t)N * D * sizeof(float));   // h2' buffer
  int*   eci      = (int*)alloc((size_t)E * sizeof(int));            // CSR src indices
  int*   rank     = (int*)alloc((size_t)E * sizeof(int));            // within-node slot
  float* dis      = (float*)alloc((size_t)N * sizeof(float));
  int*   degi     = (int*)alloc((size_t)N * sizeof(int));
  int*   rowstart = (int*)alloc(((size_t)N + 1) * sizeof(int));
  int*   bsum     = (int*)alloc((size_t)nb * sizeof(int));
  int*   boff     = (int*)alloc((size_t)nb * sizeof(int));

  hipMemsetAsync(degi, 0, (size_t)N * sizeof(int), stream);

  // CSR build (shared by both layers)
  k_deg<<<(E + 255) / 256, 256, 0, stream>>>(dstv, degi, rank, E);
  k_part<<<nb, TILE, 0, stream>>>(degi, bsum, N);
  k_scanb<<<1, TILE, 0, stream>>>(bsum, boff, nb);
  k_emit<<<nb, TILE, 0, stream>>>(degi, boff, rowstart, dis, N);
  k_fill<<<(E + 255) / 256, 256, 0, stream>>>(src, dstv, rank, rowstart, eci, E);

  const int gemmGrid = 2048;

  // layer 1 GEMM: h1' = (emb[tokens] @ W1) * dis -> A
  k_gemm1<true><<<gemmGrid, 256, 0, stream>>>(emb, tokens, W1, dis, (float4*)A, N);
  // fused: agg(A) + relu + (x2 @ W2) * dis -> B
  k_aggemm<<<gemmGrid, 256, 0, stream>>>((const float4*)A, eci, rowstart, dis,
                                         (const float4*)b1, W2, (float4*)B, N);
  // layer 2 aggregate: x3 = relu(...) -> A
  k_agg2<<<(N + 3) / 4, 256, 0, stream>>>((const float4*)B, eci, rowstart, dis,
                                          (const float4*)b2, (float4*)A, N);
  // pooling + head
  k_poolfinal<<<NGRAPHS, 256, 0, stream>>>(A, batch, lw, lb, out, N);
}